// Round 6
// baseline (391.373 us; speedup 1.0000x reference)
//
#include <hip/hip_runtime.h>
#include <stdint.h>

// B=2, S=2048, D=1024, H=16, DK=64, DH=4096. I/O fp32; internals bf16 MFMA.
// R6: FFN2 = 128x128 tile + split-K=4 with fp32 atomicAdd into zeroed d_out
// (4 blocks/CU, 2x intensity); G2 = BK=64 (2x MFMA per barrier).

typedef unsigned short u16;
typedef __attribute__((ext_vector_type(8))) short v8s;   // 8 x bf16
typedef __attribute__((ext_vector_type(4))) float v4f;

#define AS1 __attribute__((address_space(1)))
#define AS3 __attribute__((address_space(3)))

__device__ __forceinline__ void gl_lds16(const u16* g, u16* l) {
  __builtin_amdgcn_global_load_lds((const AS1 void*)g, (AS3 void*)l, 16, 0, 0);
}

__device__ __forceinline__ float bf2f(u16 u) {
  union { uint32_t i; float f; } v; v.i = ((uint32_t)u) << 16; return v.f;
}
__device__ __forceinline__ u16 f2bf(float f) {
  union { float f; uint32_t i; } v; v.f = f;
  uint32_t x = v.i;
  return (u16)((x + 0x7FFFu + ((x >> 16) & 1u)) >> 16);  // RNE
}
__device__ __forceinline__ uint32_t fbits(float f) {
  union { float f; uint32_t u; } v; v.f = f; return v.u;
}

// ---------------------------------------------------------------------------
__global__ __launch_bounds__(256) void cvt_f2b(
    const float* __restrict__ src, u16* __restrict__ dst, int n4) {
  int i = (blockIdx.x * 256 + threadIdx.x);
  if (i < n4) {
    float4 v = *(const float4*)(src + (size_t)i * 4);
    ushort4 o;
    o.x = f2bf(v.x); o.y = f2bf(v.y); o.z = f2bf(v.z); o.w = f2bf(v.w);
    *(ushort4*)(dst + (size_t)i * 4) = o;
  }
}

// ---------------------------------------------------------------------------
__global__ __launch_bounds__(256) void transpose_f2b(
    const float* __restrict__ src, u16* __restrict__ dst,
    int R, int C, int ld_s, int ld_d) {
  __shared__ float tile[32][33];
  const int tx = threadIdx.x & 31, ty = threadIdx.x >> 5;
  const int c0 = blockIdx.x * 32, r0 = blockIdx.y * 32;
#pragma unroll
  for (int j = 0; j < 32; j += 8)
    tile[ty + j][tx] = src[(size_t)(r0 + ty + j) * ld_s + c0 + tx];
  __syncthreads();
#pragma unroll
  for (int j = 0; j < 32; j += 8)
    dst[(size_t)(c0 + ty + j) * ld_d + r0 + tx] = f2bf(tile[tx][ty + j]);
}

__global__ __launch_bounds__(256) void transpose_b2b(
    const u16* __restrict__ src, u16* __restrict__ dst,
    int R, int C, int ld_s, int ld_d) {
  __shared__ u16 tile[32][33];
  const int tx = threadIdx.x & 31, ty = threadIdx.x >> 5;
  const int c0 = blockIdx.x * 32, r0 = blockIdx.y * 32;
#pragma unroll
  for (int j = 0; j < 32; j += 8)
    tile[ty + j][tx] = src[(size_t)(r0 + ty + j) * ld_s + c0 + tx];
  __syncthreads();
#pragma unroll
  for (int j = 0; j < 32; j += 8)
    dst[(size_t)(c0 + ty + j) * ld_d + r0 + tx] = tile[tx][ty + j];
}

// ---------------------------------------------------------------------------
// G1: 128x128 tile, BK=32, double-buffered. Split-K via blockIdx.z:
// k_begin = z*klen; atomic=1 -> fp32 atomicAdd epilogue (C pre-zeroed),
// bias added only by the z==0 split. ldk = row stride of A and Bt.
// ---------------------------------------------------------------------------
__global__ __launch_bounds__(256) void gemm_g1(
    const u16* __restrict__ A, const u16* __restrict__ Bt,
    const float* __restrict__ bias, void* __restrict__ C,
    int M, int N, int ldk, int klen, int relu, int accum, int out_f32,
    int atomic) {
  __shared__ u16 As[2][4096];
  __shared__ u16 Bs[2][4096];
  const int tid = threadIdx.x;
  const int w = tid >> 6, l = tid & 63;
  const int lane16 = l & 15, kgrp = l >> 4;
  const int m0 = blockIdx.y * 128, n0 = blockIdx.x * 128;
  const int k_begin = blockIdx.z * klen;
  const int wr = (w >> 1) * 64, wc = (w & 1) * 64;

  const int sr = w * 32 + (l >> 2);
  const int sc = l & 3;
  const int sgc = sc ^ ((sr & 3) ^ ((sr >> 2) & 3));
  const u16* gA = A + (size_t)(m0 + sr) * ldk + k_begin + 8 * sgc;
  const u16* gB = Bt + (size_t)(n0 + sr) * ldk + k_begin + 8 * sgc;
  const size_t rstep = (size_t)16 * ldk;
  const int fl = (lane16 & 3) ^ ((lane16 >> 2) & 3);

  v4f acc[4][4];
#pragma unroll
  for (int i = 0; i < 4; i++)
#pragma unroll
    for (int j = 0; j < 4; j++)
#pragma unroll
      for (int r = 0; r < 4; r++) acc[i][j][r] = 0.f;

  gl_lds16(gA, &As[0][w * 1024]);
  gl_lds16(gA + rstep, &As[0][w * 1024 + 512]);
  gl_lds16(gB, &Bs[0][w * 1024]);
  gl_lds16(gB + rstep, &Bs[0][w * 1024 + 512]);

  int cur = 0;
  for (int k0 = 0; k0 < klen; k0 += 32) {
    __syncthreads();
    if (k0 + 32 < klen) {
      int nxt = cur ^ 1;
      gl_lds16(gA + k0 + 32, &As[nxt][w * 1024]);
      gl_lds16(gA + k0 + 32 + rstep, &As[nxt][w * 1024 + 512]);
      gl_lds16(gB + k0 + 32, &Bs[nxt][w * 1024]);
      gl_lds16(gB + k0 + 32 + rstep, &Bs[nxt][w * 1024 + 512]);
    }
    v8s a[4], b[4];
#pragma unroll
    for (int mi = 0; mi < 4; mi++)
      a[mi] = *(const v8s*)(&As[cur][(wr + mi * 16 + lane16) * 32 + 8 * (kgrp ^ fl)]);
#pragma unroll
    for (int ni = 0; ni < 4; ni++)
      b[ni] = *(const v8s*)(&Bs[cur][(wc + ni * 16 + lane16) * 32 + 8 * (kgrp ^ fl)]);
#pragma unroll
    for (int mi = 0; mi < 4; mi++)
#pragma unroll
      for (int ni = 0; ni < 4; ni++)
        acc[mi][ni] = __builtin_amdgcn_mfma_f32_16x16x32_bf16(a[mi], b[ni], acc[mi][ni], 0, 0, 0);
    cur ^= 1;
  }

#pragma unroll
  for (int ni = 0; ni < 4; ni++) {
    int col = n0 + wc + ni * 16 + lane16;
    float bv = (bias && k_begin == 0) ? bias[col] : 0.f;
#pragma unroll
    for (int mi = 0; mi < 4; mi++) {
      int row = m0 + wr + mi * 16 + kgrp * 4;
#pragma unroll
      for (int r = 0; r < 4; r++) {
        float v = acc[mi][ni][r] + bv;
        if (relu) v = fmaxf(v, 0.f);
        size_t idx = (size_t)(row + r) * N + col;
        if (atomic) {
          atomicAdd(&((float*)C)[idx], v);
        } else if (out_f32) {
          float* Cf = (float*)C;
          if (accum) v += Cf[idx];
          Cf[idx] = v;
        } else {
          ((u16*)C)[idx] = f2bf(v);
        }
      }
    }
  }
}

// ---------------------------------------------------------------------------
// G2: 128x64 tile, BK=64 (16 MFMA/barrier), double-buffered. 48 KB LDS.
// Staging geometry identical to attn kernel's validated 64-col XOR swizzle.
// ---------------------------------------------------------------------------
__global__ __launch_bounds__(256) void gemm_g2(
    const u16* __restrict__ A, const u16* __restrict__ Bt,
    const float* __restrict__ bias, void* __restrict__ C,
    int M, int N, int K, int relu, int accum, int out_f32) {
  __shared__ u16 As[2][8192];   // 128 rows x 64
  __shared__ u16 Bs[2][4096];   // 64 rows x 64
  const int tid = threadIdx.x;
  const int w = tid >> 6, l = tid & 63;
  const int l16 = l & 15, kgrp = l >> 4;
  const int m0 = blockIdx.y * 128, n0 = blockIdx.x * 64;
  const int wr = (w >> 1) * 64, wc = (w & 1) * 32;

  // staging: instr i covers rows i*32 + w*8 + (l>>3), phys chunk l&7,
  // logical chunk = (l&7) ^ (row&7)
  const int srow = w * 8 + (l >> 3);
  const u16* gA[4];
#pragma unroll
  for (int i = 0; i < 4; i++) {
    int r = i * 32 + srow;
    gA[i] = A + (size_t)(m0 + r) * K + 8 * ((l & 7) ^ (r & 7));
  }
  const u16* gB[2];
#pragma unroll
  for (int i = 0; i < 2; i++) {
    int r = i * 32 + srow;
    gB[i] = Bt + (size_t)(n0 + r) * K + 8 * ((l & 7) ^ (r & 7));
  }

  v4f acc[4][2];
#pragma unroll
  for (int i = 0; i < 4; i++)
#pragma unroll
    for (int j = 0; j < 2; j++)
#pragma unroll
      for (int r = 0; r < 4; r++) acc[i][j][r] = 0.f;

#pragma unroll
  for (int i = 0; i < 4; i++) gl_lds16(gA[i], &As[0][(i * 256 + w * 64) * 8]);
#pragma unroll
  for (int i = 0; i < 2; i++) gl_lds16(gB[i], &Bs[0][(i * 256 + w * 64) * 8]);

  int cur = 0;
  for (int k0 = 0; k0 < K; k0 += 64) {
    __syncthreads();
    if (k0 + 64 < K) {
      int nxt = cur ^ 1;
#pragma unroll
      for (int i = 0; i < 4; i++)
        gl_lds16(gA[i] + k0 + 64, &As[nxt][(i * 256 + w * 64) * 8]);
#pragma unroll
      for (int i = 0; i < 2; i++)
        gl_lds16(gB[i] + k0 + 64, &Bs[nxt][(i * 256 + w * 64) * 8]);
    }
    v8s a[4][2], b[2][2];
#pragma unroll
    for (int ks = 0; ks < 2; ks++) {
      int ch = 8 * ((ks * 4 + kgrp) ^ (l16 & 7));
#pragma unroll
      for (int mi = 0; mi < 4; mi++)
        a[mi][ks] = *(const v8s*)(&As[cur][(wr + mi * 16 + l16) * 64 + ch]);
#pragma unroll
      for (int ni = 0; ni < 2; ni++)
        b[ni][ks] = *(const v8s*)(&Bs[cur][(wc + ni * 16 + l16) * 64 + ch]);
    }
#pragma unroll
    for (int ks = 0; ks < 2; ks++)
#pragma unroll
      for (int mi = 0; mi < 4; mi++)
#pragma unroll
        for (int ni = 0; ni < 2; ni++)
          acc[mi][ni] = __builtin_amdgcn_mfma_f32_16x16x32_bf16(a[mi][ks], b[ni][ks], acc[mi][ni], 0, 0, 0);
    cur ^= 1;
  }

#pragma unroll
  for (int ni = 0; ni < 2; ni++) {
    int col = n0 + wc + ni * 16 + l16;
    float bv = bias ? bias[col] : 0.f;
#pragma unroll
    for (int mi = 0; mi < 4; mi++) {
      int row = m0 + wr + mi * 16 + kgrp * 4;
#pragma unroll
      for (int r = 0; r < 4; r++) {
        float v = acc[mi][ni][r] + bv;
        if (relu) v = fmaxf(v, 0.f);
        size_t idx = (size_t)(row + r) * N + col;
        if (out_f32) {
          float* Cf = (float*)C;
          if (accum) v += Cf[idx];
          Cf[idx] = v;
        } else {
          ((u16*)C)[idx] = f2bf(v);
        }
      }
    }
  }
}

// ---------------------------------------------------------------------------
// Attention (unchanged R5): O = softmax(Q Q^T / sqrt(S)) Q per (b,h).
// ---------------------------------------------------------------------------
__global__ __launch_bounds__(256) void attn_kernel(
    const u16* __restrict__ Q, const u16* __restrict__ Qt,
    u16* __restrict__ O) {
  __shared__ u16 KV[2][8192];
  __shared__ __align__(16) u16 Ps[4][2304];
  const int tid = threadIdx.x;
  const int w = tid >> 6, l = tid & 63;
  const int l16 = l & 15, kgrp = l >> 4;
  const int bh = blockIdx.y, b = bh >> 4, h = bh & 15;
  const int q0 = blockIdx.x * 128;
  const size_t rowQ = (size_t)(b * 2048 + q0 + w * 32);
  const float cexp = 1.4426950408889634f / 45.254833995939045f;

  const int srow = w * 8 + (l >> 3);
  const int sch8 = 8 * ((l & 7) ^ (srow & 7));
  const u16* gK0 = Q + (size_t)(b * 2048 + srow) * 1024 + h * 64 + sch8;
  const u16* gK1 = gK0 + (size_t)32 * 1024;
  const u16* gV0 = Qt + (size_t)(h * 64 + srow) * 4096 + b * 2048 + sch8;
  const u16* gV1 = gV0 + (size_t)32 * 4096;

  v8s qb[2][2];
#pragma unroll
  for (int nj = 0; nj < 2; nj++)
#pragma unroll
    for (int ks = 0; ks < 2; ks++) {
      v8s t = *(const v8s*)(Q + (rowQ + nj * 16 + l16) * 1024 + h * 64 + ks * 32 + kgrp * 8);
#pragma unroll
      for (int j = 0; j < 8; j++) t[j] = (short)f2bf(bf2f((u16)t[j]) * cexp);
      qb[nj][ks] = t;
    }

  v4f o[2][4];
  float ls[2] = {0.f, 0.f};
#pragma unroll
  for (int i = 0; i < 2; i++)
#pragma unroll
    for (int j = 0; j < 4; j++)
#pragma unroll
      for (int r = 0; r < 4; r++) o[i][j][r] = 0.f;

  gl_lds16(gK0, &KV[0][w * 512]);
  gl_lds16(gK1, &KV[0][2048 + w * 512]);
  gl_lds16(gV0, &KV[0][4096 + w * 512]);
  gl_lds16(gV1, &KV[0][4096 + 2048 + w * 512]);

  u16* Pw = &Ps[w][0];
  int cur = 0;
  for (int kb = 0; kb < 2048; kb += 64) {
    __syncthreads();
    if (kb + 64 < 2048) {
      int nxt = cur ^ 1;
      gl_lds16(gK0 + (size_t)(kb + 64) * 1024, &KV[nxt][w * 512]);
      gl_lds16(gK1 + (size_t)(kb + 64) * 1024, &KV[nxt][2048 + w * 512]);
      gl_lds16(gV0 + (kb + 64), &KV[nxt][4096 + w * 512]);
      gl_lds16(gV1 + (kb + 64), &KV[nxt][4096 + 2048 + w * 512]);
    }
    const u16* Ks = &KV[cur][0];
    const u16* Vt = &KV[cur][4096];

    v4f st[4][2];
#pragma unroll
    for (int i = 0; i < 4; i++)
#pragma unroll
      for (int j = 0; j < 2; j++)
#pragma unroll
        for (int r = 0; r < 4; r++) st[i][j][r] = 0.f;
#pragma unroll
    for (int ks = 0; ks < 2; ks++) {
      v8s ka[4];
#pragma unroll
      for (int mi = 0; mi < 4; mi++)
        ka[mi] = *(const v8s*)(Ks + (mi * 16 + l16) * 64 + 8 * ((ks * 4 + kgrp) ^ (l16 & 7)));
#pragma unroll
      for (int mi = 0; mi < 4; mi++)
#pragma unroll
        for (int nj = 0; nj < 2; nj++)
          st[mi][nj] = __builtin_amdgcn_mfma_f32_16x16x32_bf16(ka[mi], qb[nj][ks], st[mi][nj], 0, 0, 0);
    }

#pragma unroll
    for (int mi = 0; mi < 4; mi++)
#pragma unroll
      for (int nj = 0; nj < 2; nj++) {
        float p0 = __builtin_amdgcn_exp2f(st[mi][nj][0]);
        float p1 = __builtin_amdgcn_exp2f(st[mi][nj][1]);
        float p2 = __builtin_amdgcn_exp2f(st[mi][nj][2]);
        float p3 = __builtin_amdgcn_exp2f(st[mi][nj][3]);
        ls[nj] += (p0 + p1) + (p2 + p3);
        uint2 pk;
        pk.x = __builtin_amdgcn_perm(fbits(p1), fbits(p0), 0x07060302u);
        pk.y = __builtin_amdgcn_perm(fbits(p3), fbits(p2), 0x07060302u);
        *(uint2*)(Pw + (nj * 16 + l16) * 72 + mi * 16 + kgrp * 4) = pk;
      }

#pragma unroll
    for (int t = 0; t < 2; t++) {
      v8s pa[2], vb[4];
#pragma unroll
      for (int nj = 0; nj < 2; nj++)
        pa[nj] = *(const v8s*)(Pw + (nj * 16 + l16) * 72 + t * 32 + kgrp * 8);
#pragma unroll
      for (int ni = 0; ni < 4; ni++)
        vb[ni] = *(const v8s*)(Vt + (ni * 16 + l16) * 64 + 8 * ((t * 4 + kgrp) ^ (l16 & 7)));
#pragma unroll
      for (int nj = 0; nj < 2; nj++)
#pragma unroll
        for (int ni = 0; ni < 4; ni++)
          o[nj][ni] = __builtin_amdgcn_mfma_f32_16x16x32_bf16(pa[nj], vb[ni], o[nj][ni], 0, 0, 0);
    }
    cur ^= 1;
  }

#pragma unroll
  for (int nj = 0; nj < 2; nj++) {
    float t = ls[nj];
    t += __shfl_xor(t, 16, 64);
    t += __shfl_xor(t, 32, 64);
    ls[nj] = t;
  }

#pragma unroll
  for (int nj = 0; nj < 2; nj++) {
#pragma unroll
    for (int r = 0; r < 4; r++) {
      float den = __shfl(ls[nj], kgrp * 4 + r, 64);
      float rden = 1.f / den;
#pragma unroll
      for (int ni = 0; ni < 4; ni++) {
        O[(rowQ + nj * 16 + kgrp * 4 + r) * 1024 + h * 64 + ni * 16 + l16] =
            f2bf(o[nj][ni][r] * rden);
      }
    }
  }
}

// ---------------------------------------------------------------------------
__global__ __launch_bounds__(256) void ln_residual(
    const void* __restrict__ Y, const void* __restrict__ Xr,
    const float* __restrict__ g, const float* __restrict__ bb,
    void* __restrict__ out, int yf, int xf, int of) {
  const int row = blockIdx.x, tid = threadIdx.x;
  const size_t base = (size_t)row * 1024;
  float v[4], s = 0.f, sq = 0.f;
#pragma unroll
  for (int i = 0; i < 4; i++) {
    int c = tid + i * 256;
    float ya = yf ? ((const float*)Y)[base + c] : bf2f(((const u16*)Y)[base + c]);
    float xa = xf ? ((const float*)Xr)[base + c] : bf2f(((const u16*)Xr)[base + c]);
    float x = ya + xa;
    v[i] = x; s += x; sq += x * x;
  }
#pragma unroll
  for (int off = 32; off >= 1; off >>= 1) {
    s += __shfl_down(s, off, 64);
    sq += __shfl_down(sq, off, 64);
  }
  __shared__ float rs[4], rq[4];
  const int w = tid >> 6, l = tid & 63;
  if (l == 0) { rs[w] = s; rq[w] = sq; }
  __syncthreads();
  s = rs[0] + rs[1] + rs[2] + rs[3];
  sq = rq[0] + rq[1] + rq[2] + rq[3];
  const float mu = s * (1.f / 1024.f);
  const float var = sq * (1.f / 1024.f) - mu * mu;
  const float rstd = rsqrtf(var + 1e-5f);
#pragma unroll
  for (int i = 0; i < 4; i++) {
    int c = tid + i * 256;
    float r = (v[i] - mu) * rstd * g[c] + bb[c];
    if (of) ((float*)out)[base + c] = r;
    else ((u16*)out)[base + c] = f2bf(r);
  }
}

// ---------------------------------------------------------------------------
extern "C" void kernel_launch(void* const* d_in, const int* in_sizes, int n_in,
                              void* d_out, int out_size, void* d_ws, size_t ws_size,
                              hipStream_t stream) {
  const float* x   = (const float*)d_in[0];
  const float* Wq  = (const float*)d_in[1];
  const float* bq  = (const float*)d_in[2];
  const float* Wo  = (const float*)d_in[3];
  const float* bo  = (const float*)d_in[4];
  const float* g1  = (const float*)d_in[5];
  const float* be1 = (const float*)d_in[6];
  const float* W1  = (const float*)d_in[7];
  const float* b1  = (const float*)d_in[8];
  const float* W2  = (const float*)d_in[9];
  const float* b2  = (const float*)d_in[10];
  const float* g2  = (const float*)d_in[11];
  const float* be2 = (const float*)d_in[12];
  float* out = (float*)d_out;
  u16* ws  = (u16*)d_ws;

  const size_t M1 = 1048576;
  dim3 blk(256);
  const bool big = ws_size >= (size_t)37 * M1 * 2;  // 74 MiB

  if (big) {
    u16* xb   = ws + 0;          // -> attn
    u16* Qb   = ws + 4 * M1;     // -> x1
    u16* Qt   = ws + 8 * M1;     // -> Yb
    u16* WqT  = ws + 12 * M1;    // -> WoT
    u16* W1T  = ws + 13 * M1;
    u16* W2T  = ws + 17 * M1;
    u16* Hh   = ws + 21 * M1;
    u16* attn = xb;  u16* Yb = Qt;  u16* x1 = Qb;  u16* WoT = WqT;

    // zero d_out for the FFN2 split-K atomic accumulation
    hipMemsetAsync(out, 0, (size_t)out_size * sizeof(float), stream);

    cvt_f2b<<<dim3(4096), blk, 0, stream>>>(x, xb, 1048576);
    transpose_f2b<<<dim3(32, 32), blk, 0, stream>>>(Wq, WqT, 1024, 1024, 1024, 1024);
    gemm_g2<<<dim3(16, 32), blk, 0, stream>>>(xb, WqT, bq, Qb, 4096, 1024, 1024, 0, 0, 0);

    transpose_b2b<<<dim3(32, 128), blk, 0, stream>>>(Qb, Qt, 4096, 1024, 1024, 4096);
    attn_kernel<<<dim3(16, 32), blk, 0, stream>>>(Qb, Qt, attn);

    transpose_f2b<<<dim3(32, 32), blk, 0, stream>>>(Wo, WoT, 1024, 1024, 1024, 1024);
    gemm_g2<<<dim3(16, 32), blk, 0, stream>>>(attn, WoT, bo, Yb, 4096, 1024, 1024, 0, 0, 0);
    ln_residual<<<dim3(4096), blk, 0, stream>>>(Yb, x, g1, be1, x1, 0, 1, 0);

    transpose_f2b<<<dim3(128, 32), blk, 0, stream>>>(W1, W1T, 1024, 4096, 4096, 1024);
    gemm_g1<<<dim3(32, 32, 1), blk, 0, stream>>>(x1, W1T, b1, Hh, 4096, 4096,
                                                 1024, 1024, 1, 0, 0, 0);
    transpose_f2b<<<dim3(32, 128), blk, 0, stream>>>(W2, W2T, 4096, 1024, 1024, 4096);
    gemm_g1<<<dim3(8, 32, 4), blk, 0, stream>>>(Hh, W2T, b2, out, 4096, 1024,
                                                4096, 1024, 0, 0, 1, 1);

    ln_residual<<<dim3(4096), blk, 0, stream>>>(out, x1, g2, be2, out, 1, 0, 1);
  } else {
    u16* xb   = ws + 0;
    u16* Qb   = ws + 4 * M1;
    u16* Qt   = ws + 8 * M1;
    u16* attn = xb;  u16* Yb = Qt;  u16* x1 = Qb;  u16* Hc = xb;
    u16* Wt1  = ws + 12 * M1;
    u16* Wt2  = ws + 13 * M1;

    cvt_f2b<<<dim3(4096), blk, 0, stream>>>(x, xb, 1048576);
    transpose_f2b<<<dim3(32, 32), blk, 0, stream>>>(Wq, Wt1, 1024, 1024, 1024, 1024);
    gemm_g2<<<dim3(16, 32), blk, 0, stream>>>(xb, Wt1, bq, Qb, 4096, 1024, 1024, 0, 0, 0);

    transpose_b2b<<<dim3(32, 128), blk, 0, stream>>>(Qb, Qt, 4096, 1024, 1024, 4096);
    attn_kernel<<<dim3(16, 32), blk, 0, stream>>>(Qb, Qt, attn);

    transpose_f2b<<<dim3(32, 32), blk, 0, stream>>>(Wo, Wt2, 1024, 1024, 1024, 1024);
    gemm_g2<<<dim3(16, 32), blk, 0, stream>>>(attn, Wt2, bo, Yb, 4096, 1024, 1024, 0, 0, 0);
    ln_residual<<<dim3(4096), blk, 0, stream>>>(Yb, x, g1, be1, x1, 0, 1, 0);

    for (int c = 0; c < 4; c++) {
      transpose_f2b<<<dim3(32, 32), blk, 0, stream>>>(W1 + (size_t)c * 1024, Wt1,
                                                      1024, 1024, 4096, 1024);
      gemm_g2<<<dim3(16, 32), blk, 0, stream>>>(x1, Wt1, b1 + (size_t)c * 1024, Hc,
                                                4096, 1024, 1024, 1, 0, 0);
      transpose_f2b<<<dim3(32, 32), blk, 0, stream>>>(W2 + (size_t)c * M1, Wt2,
                                                      1024, 1024, 1024, 1024);
      gemm_g2<<<dim3(16, 32), blk, 0, stream>>>(Hc, Wt2, (c == 0) ? b2 : (const float*)nullptr,
                                                out, 4096, 1024, 1024, 0, (c > 0) ? 1 : 0, 1);
    }
    ln_residual<<<dim3(4096), blk, 0, stream>>>(out, x1, g2, be2, out, 1, 0, 1);
  }
}

// Round 7
// 355.893 us; speedup vs baseline: 1.0997x; 1.0997x over previous
//
#include <hip/hip_runtime.h>
#include <stdint.h>

// B=2, S=2048, D=1024, H=16, DK=64, DH=4096. I/O fp32; internals bf16 MFMA.
// R7: split-K=2 WITHOUT atomics for FFN2 and Wo-proj -- partial 1 goes to a
// dead ws region, the following LayerNorm folds the reduction (3-input LN).
// G2/G2s = BK=64 (16 MFMA/barrier); G1 = 128x128 BK=32 (FFN1).

typedef unsigned short u16;
typedef __attribute__((ext_vector_type(8))) short v8s;   // 8 x bf16
typedef __attribute__((ext_vector_type(4))) float v4f;

#define AS1 __attribute__((address_space(1)))
#define AS3 __attribute__((address_space(3)))

__device__ __forceinline__ void gl_lds16(const u16* g, u16* l) {
  __builtin_amdgcn_global_load_lds((const AS1 void*)g, (AS3 void*)l, 16, 0, 0);
}

__device__ __forceinline__ float bf2f(u16 u) {
  union { uint32_t i; float f; } v; v.i = ((uint32_t)u) << 16; return v.f;
}
__device__ __forceinline__ u16 f2bf(float f) {
  union { float f; uint32_t i; } v; v.f = f;
  uint32_t x = v.i;
  return (u16)((x + 0x7FFFu + ((x >> 16) & 1u)) >> 16);  // RNE
}
__device__ __forceinline__ uint32_t fbits(float f) {
  union { float f; uint32_t u; } v; v.f = f; return v.u;
}

// ---------------------------------------------------------------------------
__global__ __launch_bounds__(256) void cvt_f2b(
    const float* __restrict__ src, u16* __restrict__ dst, int n4) {
  int i = (blockIdx.x * 256 + threadIdx.x);
  if (i < n4) {
    float4 v = *(const float4*)(src + (size_t)i * 4);
    ushort4 o;
    o.x = f2bf(v.x); o.y = f2bf(v.y); o.z = f2bf(v.z); o.w = f2bf(v.w);
    *(ushort4*)(dst + (size_t)i * 4) = o;
  }
}

// ---------------------------------------------------------------------------
__global__ __launch_bounds__(256) void transpose_f2b(
    const float* __restrict__ src, u16* __restrict__ dst,
    int R, int C, int ld_s, int ld_d) {
  __shared__ float tile[32][33];
  const int tx = threadIdx.x & 31, ty = threadIdx.x >> 5;
  const int c0 = blockIdx.x * 32, r0 = blockIdx.y * 32;
#pragma unroll
  for (int j = 0; j < 32; j += 8)
    tile[ty + j][tx] = src[(size_t)(r0 + ty + j) * ld_s + c0 + tx];
  __syncthreads();
#pragma unroll
  for (int j = 0; j < 32; j += 8)
    dst[(size_t)(c0 + ty + j) * ld_d + r0 + tx] = f2bf(tile[tx][ty + j]);
}

__global__ __launch_bounds__(256) void transpose_b2b(
    const u16* __restrict__ src, u16* __restrict__ dst,
    int R, int C, int ld_s, int ld_d) {
  __shared__ u16 tile[32][33];
  const int tx = threadIdx.x & 31, ty = threadIdx.x >> 5;
  const int c0 = blockIdx.x * 32, r0 = blockIdx.y * 32;
#pragma unroll
  for (int j = 0; j < 32; j += 8)
    tile[ty + j][tx] = src[(size_t)(r0 + ty + j) * ld_s + c0 + tx];
  __syncthreads();
#pragma unroll
  for (int j = 0; j < 32; j += 8)
    dst[(size_t)(c0 + ty + j) * ld_d + r0 + tx] = tile[tx][ty + j];
}

// ---------------------------------------------------------------------------
// G1: 128x128 tile, BK=32, double-buffered.
// ---------------------------------------------------------------------------
__global__ __launch_bounds__(256) void gemm_g1(
    const u16* __restrict__ A, const u16* __restrict__ Bt,
    const float* __restrict__ bias, void* __restrict__ C,
    int M, int N, int K, int relu, int out_f32) {
  __shared__ u16 As[2][4096];
  __shared__ u16 Bs[2][4096];
  const int tid = threadIdx.x;
  const int w = tid >> 6, l = tid & 63;
  const int lane16 = l & 15, kgrp = l >> 4;
  const int m0 = blockIdx.y * 128, n0 = blockIdx.x * 128;
  const int wr = (w >> 1) * 64, wc = (w & 1) * 64;

  const int sr = w * 32 + (l >> 2);
  const int sc = l & 3;
  const int sgc = sc ^ ((sr & 3) ^ ((sr >> 2) & 3));
  const u16* gA = A + (size_t)(m0 + sr) * K + 8 * sgc;
  const u16* gB = Bt + (size_t)(n0 + sr) * K + 8 * sgc;
  const size_t rstep = (size_t)16 * K;
  const int fl = (lane16 & 3) ^ ((lane16 >> 2) & 3);

  v4f acc[4][4];
#pragma unroll
  for (int i = 0; i < 4; i++)
#pragma unroll
    for (int j = 0; j < 4; j++)
#pragma unroll
      for (int r = 0; r < 4; r++) acc[i][j][r] = 0.f;

  gl_lds16(gA, &As[0][w * 1024]);
  gl_lds16(gA + rstep, &As[0][w * 1024 + 512]);
  gl_lds16(gB, &Bs[0][w * 1024]);
  gl_lds16(gB + rstep, &Bs[0][w * 1024 + 512]);

  int cur = 0;
  for (int k0 = 0; k0 < K; k0 += 32) {
    __syncthreads();
    if (k0 + 32 < K) {
      int nxt = cur ^ 1;
      gl_lds16(gA + k0 + 32, &As[nxt][w * 1024]);
      gl_lds16(gA + k0 + 32 + rstep, &As[nxt][w * 1024 + 512]);
      gl_lds16(gB + k0 + 32, &Bs[nxt][w * 1024]);
      gl_lds16(gB + k0 + 32 + rstep, &Bs[nxt][w * 1024 + 512]);
    }
    v8s a[4], b[4];
#pragma unroll
    for (int mi = 0; mi < 4; mi++)
      a[mi] = *(const v8s*)(&As[cur][(wr + mi * 16 + lane16) * 32 + 8 * (kgrp ^ fl)]);
#pragma unroll
    for (int ni = 0; ni < 4; ni++)
      b[ni] = *(const v8s*)(&Bs[cur][(wc + ni * 16 + lane16) * 32 + 8 * (kgrp ^ fl)]);
#pragma unroll
    for (int mi = 0; mi < 4; mi++)
#pragma unroll
      for (int ni = 0; ni < 4; ni++)
        acc[mi][ni] = __builtin_amdgcn_mfma_f32_16x16x32_bf16(a[mi], b[ni], acc[mi][ni], 0, 0, 0);
    cur ^= 1;
  }

#pragma unroll
  for (int ni = 0; ni < 4; ni++) {
    int col = n0 + wc + ni * 16 + lane16;
    float bv = bias ? bias[col] : 0.f;
#pragma unroll
    for (int mi = 0; mi < 4; mi++) {
      int row = m0 + wr + mi * 16 + kgrp * 4;
#pragma unroll
      for (int r = 0; r < 4; r++) {
        float v = acc[mi][ni][r] + bv;
        if (relu) v = fmaxf(v, 0.f);
        size_t idx = (size_t)(row + r) * N + col;
        if (out_f32) ((float*)C)[idx] = v;
        else ((u16*)C)[idx] = f2bf(v);
      }
    }
  }
}

// ---------------------------------------------------------------------------
// G2: 128x64 tile, BK=64, double-buffered (unsplit; Qproj + small path).
// ---------------------------------------------------------------------------
__global__ __launch_bounds__(256) void gemm_g2(
    const u16* __restrict__ A, const u16* __restrict__ Bt,
    const float* __restrict__ bias, void* __restrict__ C,
    int M, int N, int K, int relu, int accum, int out_f32) {
  __shared__ u16 As[2][8192];
  __shared__ u16 Bs[2][4096];
  const int tid = threadIdx.x;
  const int w = tid >> 6, l = tid & 63;
  const int l16 = l & 15, kgrp = l >> 4;
  const int m0 = blockIdx.y * 128, n0 = blockIdx.x * 64;
  const int wr = (w >> 1) * 64, wc = (w & 1) * 32;

  const int srow = w * 8 + (l >> 3);
  const u16* gA[4];
#pragma unroll
  for (int i = 0; i < 4; i++) {
    int r = i * 32 + srow;
    gA[i] = A + (size_t)(m0 + r) * K + 8 * ((l & 7) ^ (r & 7));
  }
  const u16* gB[2];
#pragma unroll
  for (int i = 0; i < 2; i++) {
    int r = i * 32 + srow;
    gB[i] = Bt + (size_t)(n0 + r) * K + 8 * ((l & 7) ^ (r & 7));
  }

  v4f acc[4][2];
#pragma unroll
  for (int i = 0; i < 4; i++)
#pragma unroll
    for (int j = 0; j < 2; j++)
#pragma unroll
      for (int r = 0; r < 4; r++) acc[i][j][r] = 0.f;

#pragma unroll
  for (int i = 0; i < 4; i++) gl_lds16(gA[i], &As[0][(i * 256 + w * 64) * 8]);
#pragma unroll
  for (int i = 0; i < 2; i++) gl_lds16(gB[i], &Bs[0][(i * 256 + w * 64) * 8]);

  int cur = 0;
  for (int k0 = 0; k0 < K; k0 += 64) {
    __syncthreads();
    if (k0 + 64 < K) {
      int nxt = cur ^ 1;
#pragma unroll
      for (int i = 0; i < 4; i++)
        gl_lds16(gA[i] + k0 + 64, &As[nxt][(i * 256 + w * 64) * 8]);
#pragma unroll
      for (int i = 0; i < 2; i++)
        gl_lds16(gB[i] + k0 + 64, &Bs[nxt][(i * 256 + w * 64) * 8]);
    }
    v8s a[4][2], b[2][2];
#pragma unroll
    for (int ks = 0; ks < 2; ks++) {
      int ch = 8 * ((ks * 4 + kgrp) ^ (l16 & 7));
#pragma unroll
      for (int mi = 0; mi < 4; mi++)
        a[mi][ks] = *(const v8s*)(&As[cur][(wr + mi * 16 + l16) * 64 + ch]);
#pragma unroll
      for (int ni = 0; ni < 2; ni++)
        b[ni][ks] = *(const v8s*)(&Bs[cur][(wc + ni * 16 + l16) * 64 + ch]);
    }
#pragma unroll
    for (int ks = 0; ks < 2; ks++)
#pragma unroll
      for (int mi = 0; mi < 4; mi++)
#pragma unroll
        for (int ni = 0; ni < 2; ni++)
          acc[mi][ni] = __builtin_amdgcn_mfma_f32_16x16x32_bf16(a[mi][ks], b[ni][ks], acc[mi][ni], 0, 0, 0);
    cur ^= 1;
  }

#pragma unroll
  for (int ni = 0; ni < 2; ni++) {
    int col = n0 + wc + ni * 16 + l16;
    float bv = bias ? bias[col] : 0.f;
#pragma unroll
    for (int mi = 0; mi < 4; mi++) {
      int row = m0 + wr + mi * 16 + kgrp * 4;
#pragma unroll
      for (int r = 0; r < 4; r++) {
        float v = acc[mi][ni][r] + bv;
        if (relu) v = fmaxf(v, 0.f);
        size_t idx = (size_t)(row + r) * N + col;
        if (out_f32) {
          float* Cf = (float*)C;
          if (accum) v += Cf[idx];
          Cf[idx] = v;
        } else {
          ((u16*)C)[idx] = f2bf(v);
        }
      }
    }
  }
}

// ---------------------------------------------------------------------------
// G2s: split-K=2 variant of G2 (blockIdx.z = split). z=0 -> C0 (+bias,
// fp32 or bf16); z=1 -> C1 (bf16 partial). No atomics; reduction is folded
// into the following 3-input LayerNorm.
// ---------------------------------------------------------------------------
__global__ __launch_bounds__(256) void gemm_g2s(
    const u16* __restrict__ A, const u16* __restrict__ Bt,
    const float* __restrict__ bias, void* __restrict__ C0,
    u16* __restrict__ C1, int M, int N, int ldk, int klen, int c0_f32) {
  __shared__ u16 As[2][8192];
  __shared__ u16 Bs[2][4096];
  const int tid = threadIdx.x;
  const int w = tid >> 6, l = tid & 63;
  const int l16 = l & 15, kgrp = l >> 4;
  const int m0 = blockIdx.y * 128, n0 = blockIdx.x * 64;
  const int z = blockIdx.z;
  const int k_begin = z * klen;
  const int wr = (w >> 1) * 64, wc = (w & 1) * 32;

  const int srow = w * 8 + (l >> 3);
  const u16* gA[4];
#pragma unroll
  for (int i = 0; i < 4; i++) {
    int r = i * 32 + srow;
    gA[i] = A + (size_t)(m0 + r) * ldk + k_begin + 8 * ((l & 7) ^ (r & 7));
  }
  const u16* gB[2];
#pragma unroll
  for (int i = 0; i < 2; i++) {
    int r = i * 32 + srow;
    gB[i] = Bt + (size_t)(n0 + r) * ldk + k_begin + 8 * ((l & 7) ^ (r & 7));
  }

  v4f acc[4][2];
#pragma unroll
  for (int i = 0; i < 4; i++)
#pragma unroll
    for (int j = 0; j < 2; j++)
#pragma unroll
      for (int r = 0; r < 4; r++) acc[i][j][r] = 0.f;

#pragma unroll
  for (int i = 0; i < 4; i++) gl_lds16(gA[i], &As[0][(i * 256 + w * 64) * 8]);
#pragma unroll
  for (int i = 0; i < 2; i++) gl_lds16(gB[i], &Bs[0][(i * 256 + w * 64) * 8]);

  int cur = 0;
  for (int k0 = 0; k0 < klen; k0 += 64) {
    __syncthreads();
    if (k0 + 64 < klen) {
      int nxt = cur ^ 1;
#pragma unroll
      for (int i = 0; i < 4; i++)
        gl_lds16(gA[i] + k0 + 64, &As[nxt][(i * 256 + w * 64) * 8]);
#pragma unroll
      for (int i = 0; i < 2; i++)
        gl_lds16(gB[i] + k0 + 64, &Bs[nxt][(i * 256 + w * 64) * 8]);
    }
    v8s a[4][2], b[2][2];
#pragma unroll
    for (int ks = 0; ks < 2; ks++) {
      int ch = 8 * ((ks * 4 + kgrp) ^ (l16 & 7));
#pragma unroll
      for (int mi = 0; mi < 4; mi++)
        a[mi][ks] = *(const v8s*)(&As[cur][(wr + mi * 16 + l16) * 64 + ch]);
#pragma unroll
      for (int ni = 0; ni < 2; ni++)
        b[ni][ks] = *(const v8s*)(&Bs[cur][(wc + ni * 16 + l16) * 64 + ch]);
    }
#pragma unroll
    for (int ks = 0; ks < 2; ks++)
#pragma unroll
      for (int mi = 0; mi < 4; mi++)
#pragma unroll
        for (int ni = 0; ni < 2; ni++)
          acc[mi][ni] = __builtin_amdgcn_mfma_f32_16x16x32_bf16(a[mi][ks], b[ni][ks], acc[mi][ni], 0, 0, 0);
    cur ^= 1;
  }

#pragma unroll
  for (int ni = 0; ni < 2; ni++) {
    int col = n0 + wc + ni * 16 + l16;
    float bv = (bias && z == 0) ? bias[col] : 0.f;
#pragma unroll
    for (int mi = 0; mi < 4; mi++) {
      int row = m0 + wr + mi * 16 + kgrp * 4;
#pragma unroll
      for (int r = 0; r < 4; r++) {
        float v = acc[mi][ni][r] + bv;
        size_t idx = (size_t)(row + r) * N + col;
        if (z == 0) {
          if (c0_f32) ((float*)C0)[idx] = v;
          else ((u16*)C0)[idx] = f2bf(v);
        } else {
          C1[idx] = f2bf(v);
        }
      }
    }
  }
}

// ---------------------------------------------------------------------------
// Attention (R5 structure): O = softmax(Q Q^T / sqrt(S)) Q per (b,h).
// ---------------------------------------------------------------------------
__global__ __launch_bounds__(256) void attn_kernel(
    const u16* __restrict__ Q, const u16* __restrict__ Qt,
    u16* __restrict__ O) {
  __shared__ u16 KV[2][8192];
  __shared__ __align__(16) u16 Ps[4][2304];
  const int tid = threadIdx.x;
  const int w = tid >> 6, l = tid & 63;
  const int l16 = l & 15, kgrp = l >> 4;
  const int bh = blockIdx.y, b = bh >> 4, h = bh & 15;
  const int q0 = blockIdx.x * 128;
  const size_t rowQ = (size_t)(b * 2048 + q0 + w * 32);
  const float cexp = 1.4426950408889634f / 45.254833995939045f;

  const int srow = w * 8 + (l >> 3);
  const int sch8 = 8 * ((l & 7) ^ (srow & 7));
  const u16* gK0 = Q + (size_t)(b * 2048 + srow) * 1024 + h * 64 + sch8;
  const u16* gK1 = gK0 + (size_t)32 * 1024;
  const u16* gV0 = Qt + (size_t)(h * 64 + srow) * 4096 + b * 2048 + sch8;
  const u16* gV1 = gV0 + (size_t)32 * 4096;

  v8s qb[2][2];
#pragma unroll
  for (int nj = 0; nj < 2; nj++)
#pragma unroll
    for (int ks = 0; ks < 2; ks++) {
      v8s t = *(const v8s*)(Q + (rowQ + nj * 16 + l16) * 1024 + h * 64 + ks * 32 + kgrp * 8);
#pragma unroll
      for (int j = 0; j < 8; j++) t[j] = (short)f2bf(bf2f((u16)t[j]) * cexp);
      qb[nj][ks] = t;
    }

  v4f o[2][4];
  float ls[2] = {0.f, 0.f};
#pragma unroll
  for (int i = 0; i < 2; i++)
#pragma unroll
    for (int j = 0; j < 4; j++)
#pragma unroll
      for (int r = 0; r < 4; r++) o[i][j][r] = 0.f;

  gl_lds16(gK0, &KV[0][w * 512]);
  gl_lds16(gK1, &KV[0][2048 + w * 512]);
  gl_lds16(gV0, &KV[0][4096 + w * 512]);
  gl_lds16(gV1, &KV[0][4096 + 2048 + w * 512]);

  u16* Pw = &Ps[w][0];
  int cur = 0;
  for (int kb = 0; kb < 2048; kb += 64) {
    __syncthreads();
    if (kb + 64 < 2048) {
      int nxt = cur ^ 1;
      gl_lds16(gK0 + (size_t)(kb + 64) * 1024, &KV[nxt][w * 512]);
      gl_lds16(gK1 + (size_t)(kb + 64) * 1024, &KV[nxt][2048 + w * 512]);
      gl_lds16(gV0 + (kb + 64), &KV[nxt][4096 + w * 512]);
      gl_lds16(gV1 + (kb + 64), &KV[nxt][4096 + 2048 + w * 512]);
    }
    const u16* Ks = &KV[cur][0];
    const u16* Vt = &KV[cur][4096];

    v4f st[4][2];
#pragma unroll
    for (int i = 0; i < 4; i++)
#pragma unroll
      for (int j = 0; j < 2; j++)
#pragma unroll
        for (int r = 0; r < 4; r++) st[i][j][r] = 0.f;
#pragma unroll
    for (int ks = 0; ks < 2; ks++) {
      v8s ka[4];
#pragma unroll
      for (int mi = 0; mi < 4; mi++)
        ka[mi] = *(const v8s*)(Ks + (mi * 16 + l16) * 64 + 8 * ((ks * 4 + kgrp) ^ (l16 & 7)));
#pragma unroll
      for (int mi = 0; mi < 4; mi++)
#pragma unroll
        for (int nj = 0; nj < 2; nj++)
          st[mi][nj] = __builtin_amdgcn_mfma_f32_16x16x32_bf16(ka[mi], qb[nj][ks], st[mi][nj], 0, 0, 0);
    }

#pragma unroll
    for (int mi = 0; mi < 4; mi++)
#pragma unroll
      for (int nj = 0; nj < 2; nj++) {
        float p0 = __builtin_amdgcn_exp2f(st[mi][nj][0]);
        float p1 = __builtin_amdgcn_exp2f(st[mi][nj][1]);
        float p2 = __builtin_amdgcn_exp2f(st[mi][nj][2]);
        float p3 = __builtin_amdgcn_exp2f(st[mi][nj][3]);
        ls[nj] += (p0 + p1) + (p2 + p3);
        uint2 pk;
        pk.x = __builtin_amdgcn_perm(fbits(p1), fbits(p0), 0x07060302u);
        pk.y = __builtin_amdgcn_perm(fbits(p3), fbits(p2), 0x07060302u);
        *(uint2*)(Pw + (nj * 16 + l16) * 72 + mi * 16 + kgrp * 4) = pk;
      }

#pragma unroll
    for (int t = 0; t < 2; t++) {
      v8s pa[2], vb[4];
#pragma unroll
      for (int nj = 0; nj < 2; nj++)
        pa[nj] = *(const v8s*)(Pw + (nj * 16 + l16) * 72 + t * 32 + kgrp * 8);
#pragma unroll
      for (int ni = 0; ni < 4; ni++)
        vb[ni] = *(const v8s*)(Vt + (ni * 16 + l16) * 64 + 8 * ((t * 4 + kgrp) ^ (l16 & 7)));
#pragma unroll
      for (int nj = 0; nj < 2; nj++)
#pragma unroll
        for (int ni = 0; ni < 4; ni++)
          o[nj][ni] = __builtin_amdgcn_mfma_f32_16x16x32_bf16(pa[nj], vb[ni], o[nj][ni], 0, 0, 0);
    }
    cur ^= 1;
  }

#pragma unroll
  for (int nj = 0; nj < 2; nj++) {
    float t = ls[nj];
    t += __shfl_xor(t, 16, 64);
    t += __shfl_xor(t, 32, 64);
    ls[nj] = t;
  }

#pragma unroll
  for (int nj = 0; nj < 2; nj++) {
#pragma unroll
    for (int r = 0; r < 4; r++) {
      float den = __shfl(ls[nj], kgrp * 4 + r, 64);
      float rden = 1.f / den;
#pragma unroll
      for (int ni = 0; ni < 4; ni++) {
        O[(rowQ + nj * 16 + kgrp * 4 + r) * 1024 + h * 64 + ni * 16 + l16] =
            f2bf(o[nj][ni][r] * rden);
      }
    }
  }
}

// ---------------------------------------------------------------------------
// out = LayerNorm(Y [+ Y2] + Xr) * g + b; row length 1024; dtype flags
// (1 = fp32, 0 = bf16). Y2 nullable. In-place safe.
// ---------------------------------------------------------------------------
__global__ __launch_bounds__(256) void ln_residual(
    const void* __restrict__ Y, const void* __restrict__ Y2,
    const void* __restrict__ Xr,
    const float* __restrict__ g, const float* __restrict__ bb,
    void* __restrict__ out, int yf, int y2f, int xf, int of) {
  const int row = blockIdx.x, tid = threadIdx.x;
  const size_t base = (size_t)row * 1024;
  float v[4], s = 0.f, sq = 0.f;
#pragma unroll
  for (int i = 0; i < 4; i++) {
    int c = tid + i * 256;
    float ya = yf ? ((const float*)Y)[base + c] : bf2f(((const u16*)Y)[base + c]);
    float xa = xf ? ((const float*)Xr)[base + c] : bf2f(((const u16*)Xr)[base + c]);
    float x = ya + xa;
    if (Y2) {
      float y2a = y2f ? ((const float*)Y2)[base + c] : bf2f(((const u16*)Y2)[base + c]);
      x += y2a;
    }
    v[i] = x; s += x; sq += x * x;
  }
#pragma unroll
  for (int off = 32; off >= 1; off >>= 1) {
    s += __shfl_down(s, off, 64);
    sq += __shfl_down(sq, off, 64);
  }
  __shared__ float rs[4], rq[4];
  const int w = tid >> 6, l = tid & 63;
  if (l == 0) { rs[w] = s; rq[w] = sq; }
  __syncthreads();
  s = rs[0] + rs[1] + rs[2] + rs[3];
  sq = rq[0] + rq[1] + rq[2] + rq[3];
  const float mu = s * (1.f / 1024.f);
  const float var = sq * (1.f / 1024.f) - mu * mu;
  const float rstd = rsqrtf(var + 1e-5f);
#pragma unroll
  for (int i = 0; i < 4; i++) {
    int c = tid + i * 256;
    float r = (v[i] - mu) * rstd * g[c] + bb[c];
    if (of) ((float*)out)[base + c] = r;
    else ((u16*)out)[base + c] = f2bf(r);
  }
}

// ---------------------------------------------------------------------------
extern "C" void kernel_launch(void* const* d_in, const int* in_sizes, int n_in,
                              void* d_out, int out_size, void* d_ws, size_t ws_size,
                              hipStream_t stream) {
  const float* x   = (const float*)d_in[0];
  const float* Wq  = (const float*)d_in[1];
  const float* bq  = (const float*)d_in[2];
  const float* Wo  = (const float*)d_in[3];
  const float* bo  = (const float*)d_in[4];
  const float* g1  = (const float*)d_in[5];
  const float* be1 = (const float*)d_in[6];
  const float* W1  = (const float*)d_in[7];
  const float* b1  = (const float*)d_in[8];
  const float* W2  = (const float*)d_in[9];
  const float* b2  = (const float*)d_in[10];
  const float* g2  = (const float*)d_in[11];
  const float* be2 = (const float*)d_in[12];
  float* out = (float*)d_out;
  u16* ws  = (u16*)d_ws;

  const size_t M1 = 1048576;
  dim3 blk(256);
  const bool big = ws_size >= (size_t)37 * M1 * 2;  // 74 MiB

  if (big) {
    u16* xb   = ws + 0;          // [0..4M)  -> attn
    u16* Qb   = ws + 4 * M1;     // [4..8M)  -> x1
    u16* Qt   = ws + 8 * M1;     // [8..12M) -> Yb (Wo P0) -> P1_ffn2
    u16* WqT  = ws + 12 * M1;    // [12..13M) -> WoT
    u16* W1T  = ws + 13 * M1;    // [13..17M) (P1_wo lives here before W1T is written)
    u16* W2T  = ws + 17 * M1;    // [17..21M)
    u16* Hh   = ws + 21 * M1;    // [21..37M)
    u16* attn = xb;  u16* Yb = Qt;  u16* x1 = Qb;  u16* WoT = WqT;
    u16* P1wo = W1T;             // dead until transpose(W1) after LN1
    u16* P1f2 = Qt;              // Yb dead after LN1

    cvt_f2b<<<dim3(4096), blk, 0, stream>>>(x, xb, 1048576);
    transpose_f2b<<<dim3(32, 32), blk, 0, stream>>>(Wq, WqT, 1024, 1024, 1024, 1024);
    gemm_g2<<<dim3(16, 32), blk, 0, stream>>>(xb, WqT, bq, Qb, 4096, 1024, 1024, 0, 0, 0);

    transpose_b2b<<<dim3(32, 128), blk, 0, stream>>>(Qb, Qt, 4096, 1024, 1024, 4096);
    attn_kernel<<<dim3(16, 32), blk, 0, stream>>>(Qb, Qt, attn);

    // Wo projection: split-K=2, P0 -> Yb (bf16, +bias), P1 -> P1wo (bf16)
    transpose_f2b<<<dim3(32, 32), blk, 0, stream>>>(Wo, WoT, 1024, 1024, 1024, 1024);
    gemm_g2s<<<dim3(16, 32, 2), blk, 0, stream>>>(attn, WoT, bo, Yb, P1wo,
                                                  4096, 1024, 1024, 512, 0);
    ln_residual<<<dim3(4096), blk, 0, stream>>>(Yb, P1wo, x, g1, be1, x1, 0, 0, 1, 0);

    // FFN1: full-K 128x128
    transpose_f2b<<<dim3(128, 32), blk, 0, stream>>>(W1, W1T, 1024, 4096, 4096, 1024);
    gemm_g1<<<dim3(32, 32), blk, 0, stream>>>(x1, W1T, b1, Hh, 4096, 4096, 1024, 1, 0);

    // FFN2: split-K=2, P0 -> out (fp32, +bias), P1 -> P1f2 (bf16)
    transpose_f2b<<<dim3(32, 128), blk, 0, stream>>>(W2, W2T, 4096, 1024, 1024, 4096);
    gemm_g2s<<<dim3(16, 32, 2), blk, 0, stream>>>(Hh, W2T, b2, out, P1f2,
                                                  4096, 1024, 4096, 2048, 1);

    ln_residual<<<dim3(4096), blk, 0, stream>>>(out, P1f2, x1, g2, be2, out, 1, 0, 0, 1);
  } else {
    u16* xb   = ws + 0;
    u16* Qb   = ws + 4 * M1;
    u16* Qt   = ws + 8 * M1;
    u16* attn = xb;  u16* Yb = Qt;  u16* x1 = Qb;  u16* Hc = xb;
    u16* Wt1  = ws + 12 * M1;
    u16* Wt2  = ws + 13 * M1;

    cvt_f2b<<<dim3(4096), blk, 0, stream>>>(x, xb, 1048576);
    transpose_f2b<<<dim3(32, 32), blk, 0, stream>>>(Wq, Wt1, 1024, 1024, 1024, 1024);
    gemm_g2<<<dim3(16, 32), blk, 0, stream>>>(xb, Wt1, bq, Qb, 4096, 1024, 1024, 0, 0, 0);

    transpose_b2b<<<dim3(32, 128), blk, 0, stream>>>(Qb, Qt, 4096, 1024, 1024, 4096);
    attn_kernel<<<dim3(16, 32), blk, 0, stream>>>(Qb, Qt, attn);

    transpose_f2b<<<dim3(32, 32), blk, 0, stream>>>(Wo, Wt2, 1024, 1024, 1024, 1024);
    gemm_g2<<<dim3(16, 32), blk, 0, stream>>>(attn, Wt2, bo, Yb, 4096, 1024, 1024, 0, 0, 0);
    ln_residual<<<dim3(4096), blk, 0, stream>>>(Yb, nullptr, x, g1, be1, x1, 0, 0, 1, 0);

    for (int c = 0; c < 4; c++) {
      transpose_f2b<<<dim3(32, 32), blk, 0, stream>>>(W1 + (size_t)c * 1024, Wt1,
                                                      1024, 1024, 4096, 1024);
      gemm_g2<<<dim3(16, 32), blk, 0, stream>>>(x1, Wt1, b1 + (size_t)c * 1024, Hc,
                                                4096, 1024, 1024, 1, 0, 0);
      transpose_f2b<<<dim3(32, 32), blk, 0, stream>>>(W2 + (size_t)c * M1, Wt2,
                                                      1024, 1024, 1024, 1024);
      gemm_g2<<<dim3(16, 32), blk, 0, stream>>>(Hc, Wt2, (c == 0) ? b2 : (const float*)nullptr,
                                                out, 4096, 1024, 1024, 0, (c > 0) ? 1 : 0, 1);
    }
    ln_residual<<<dim3(4096), blk, 0, stream>>>(out, nullptr, x1, g2, be2, out, 1, 0, 0, 1);
  }
}